// Round 12
// baseline (392.605 us; speedup 1.0000x reference)
//
#include <hip/hip_runtime.h>
#include <hip/hip_bf16.h>
#include <stdint.h>

// ---------------------------------------------------------------------------
// FacebookAdaptiveSoftmax forward on MI355X (gfx950) — R12
//   out[4096, 50259] = concat(x@head_w^T, (x@t0w1^T)@t0w2^T * m0, (x@t1w1^T)@t1w2^T * m1)
//   new_head_target[4096] appended flat (as float)
// R12 = R11 with:
//   * NT stores reverted to plain stores everywhere (L3 tail epilogue, L2
//     fill blocks). Hypothesis: nt (no-allocate) + forced scalar dword
//     stores (odd ldc) defeats L2 write aggregation -> DRAM-burst write
//     amplification -> the ~2TB/s effective write rate inferred for L3.
//   * L0+L1 merged into one 1024-thread launch (block 0 = scan, rest casts).
// ---------------------------------------------------------------------------

typedef float  f32x4   __attribute__((ext_vector_type(4)));
typedef short  short8  __attribute__((ext_vector_type(8)));
typedef unsigned short ushort8 __attribute__((ext_vector_type(8)));

#define CUT0 10000
#define CUT1 40000
#define CUT2 50257
#define LDC   50259L

__device__ __forceinline__ void gload16(const void* g, void* l) {
    __builtin_amdgcn_global_load_lds(
        (__attribute__((address_space(1))) void*)(g),
        (__attribute__((address_space(3))) void*)(l), 16, 0, 0);
}

__device__ __forceinline__ unsigned short f2bf(float f) {
    unsigned int u = __float_as_uint(f);
    u += 0x7fffu + ((u >> 16) & 1u);   // round-to-nearest-even
    return (unsigned short)(u >> 16);
}

__device__ __forceinline__ short8 dsr128(unsigned addr) {
    f32x4 r;
    asm volatile("ds_read_b128 %0, %1" : "=v"(r) : "v"(addr));
    return __builtin_bit_cast(short8, r);
}

__device__ __forceinline__ f32x4 mfma16(short8 a, short8 b, f32x4 c) {
    return __builtin_amdgcn_mfma_f32_16x16x32_bf16(a, b, c, 0, 0, 0);
}

// ===========================================================================
// L0+L1 merged: block 0 = scan (target remap + compaction lists, 1024 thr),
// blocks 1.. = fused casts (5 segments, f32 -> bf16, zero row padding).
// ===========================================================================
struct CastSeg {
    const float* srcA;
    const float* srcB;
    unsigned short* dst;
    long rowsA, rowsB, total8;
    int lk, pad;
};
struct CastArgs {
    CastSeg s[5];
    long grand8;
};

__global__ __launch_bounds__(1024)
void scan_cast_kernel(CastArgs a, const int* __restrict__ tgt,
                      float* __restrict__ outT,
                      int* __restrict__ in0, int* __restrict__ z0,
                      int* __restrict__ in1, int* __restrict__ z1,
                      int* __restrict__ cnts) {
    if (blockIdx.x == 0) {
        __shared__ int w0[16], w1[16];
        const int t = threadIdx.x;
        int f0[4], f1[4];
        int c0 = 0, c1 = 0;
#pragma unroll
        for (int j = 0; j < 4; ++j) {
            const int r = t * 4 + j;
            const int v = tgt[r];
            const int b0 = (v >= CUT0) && (v < CUT1);
            const int b1 = (v >= CUT1) && (v < CUT2);
            f0[j] = b0; f1[j] = b1;
            c0 += b0; c1 += b1;
            outT[r] = (float)(b0 ? CUT0 : (b1 ? CUT0 + 1 : v));
        }
        const int lane = t & 63, w = t >> 6;
        int s0 = c0, s1 = c1;
        for (int d = 1; d < 64; d <<= 1) {
            const int u0 = __shfl_up(s0, d, 64);
            const int u1 = __shfl_up(s1, d, 64);
            if (lane >= d) { s0 += u0; s1 += u1; }
        }
        if (lane == 63) { w0[w] = s0; w1[w] = s1; }
        __syncthreads();
        if (t == 0) {
            int a0 = 0, a1 = 0;
            for (int i = 0; i < 16; ++i) {
                const int x0 = w0[i]; w0[i] = a0; a0 += x0;
                const int x1 = w1[i]; w1[i] = a1; a1 += x1;
            }
            cnts[0] = a0; cnts[1] = a1;
        }
        __syncthreads();
        int run0 = w0[w] + (s0 - c0);
        int run1 = w1[w] + (s1 - c1);
#pragma unroll
        for (int j = 0; j < 4; ++j) {
            const int r = t * 4 + j;
            if (f0[j]) in0[run0++] = r; else z0[r - run0] = r;
            if (f1[j]) in1[run1++] = r; else z1[r - run1] = r;
        }
        return;
    }
    // ---- casts (grid-stride over 16B chunks) ----
    long i = (blockIdx.x - 1) * 1024L + threadIdx.x;
    const long stride = ((long)gridDim.x - 1) * 1024L;
    for (; i < a.grand8; i += stride) {
        long off = i;
        int s = 0;
        while (s < 4 && off >= a.s[s].total8) { off -= a.s[s].total8; s++; }
        const CastSeg& sg = a.s[s];
        const long e   = off << 3;
        const long row = e >> sg.lk;
        ushort8 o;
        const float* src = nullptr;
        long r2 = row;
        if (row < sg.rowsA)      src = sg.srcA;
        else if (row < sg.rowsB) { src = sg.srcB; r2 = row - sg.rowsA; }
        if (src) {
            const long col = e & ((1L << sg.lk) - 1);
            const float* p = src + (r2 << sg.lk) + col;
            const float4 v0 = *(const float4*)(p);
            const float4 v1 = *(const float4*)(p + 4);
            o[0] = f2bf(v0.x); o[1] = f2bf(v0.y); o[2] = f2bf(v0.z); o[3] = f2bf(v0.w);
            o[4] = f2bf(v1.x); o[5] = f2bf(v1.y); o[6] = f2bf(v1.z); o[7] = f2bf(v1.w);
        } else {
            o = (ushort8)0;
        }
        *(ushort8*)(sg.dst + e) = o;
    }
}

// ===========================================================================
// L2: 8-phase 256x256 BK=64 GEMM (head f32-out | h01 bf16-out) + interleaved
// dedicated FILL blocks (zero masked tail rows, plain stores).
// Grid 2240 = 224 periods x 10 ids: pos {0,3,6} = GEMM (672), others = fill.
// ===========================================================================
#define STAGE2(MATP, LDM, RB, KCOL, LOFF)                                          \
    do {                                                                           \
        const unsigned short* _s0 = (MATP) + ((long)((RB) + (tid >> 3))) * (LDM) + (KCOL); \
        gload16(_s0, smem + (LOFF) + wave * 1024);                                 \
        const unsigned short* _s1 = (MATP) + ((long)((RB) + 64 + (tid >> 3))) * (LDM) + (KCOL); \
        gload16(_s1, smem + (LOFF) + 8192 + wave * 1024);                          \
    } while (0)

__global__ __launch_bounds__(512, 2)
void gemm8_dual_kernel(const unsigned short* __restrict__ A0,
                       const unsigned short* __restrict__ B0,
                       float* __restrict__ C0,
                       int nkt0, int lda0, int ldb0, int width0, int NB0, int nblk0,
                       const unsigned short* __restrict__ A1,
                       const unsigned short* __restrict__ B1,
                       unsigned short* __restrict__ C1,
                       int nkt1, int lda1, int ldb1, long ldc1, int width1, int NB1,
                       const int* __restrict__ z0, const int* __restrict__ z1,
                       const int* __restrict__ cnts, float* __restrict__ outFull) {
    __shared__ char smem[131072];

    const int tid  = threadIdx.x;
    const int lane = tid & 63;
    const int wave = tid >> 6;
    const int wr   = wave >> 2;
    const int wc   = wave & 3;

    // ---- id -> {GEMM gid | fill fidx} (period-10 interleave) ----
    const int pid = blockIdx.x / 10;
    const int pos = blockIdx.x - 10 * pid;
    const bool isGemm = (pos == 0) || (pos == 3) || (pos == 6);

    if (!isGemm) {
        const int fmap = (pos < 3) ? (pos - 1) : (pos < 6 ? pos - 2 : pos - 3);
        const int fidx = pid * 7 + fmap;
        const bool isT0 = fidx < 768;
        const int zc = 4096 - cnts[isT0 ? 0 : 1];
        const int* zl = isT0 ? z0 : z1;
        float* base0 = outFull + (isT0 ? 10002 : 40002);
        const int width = isT0 ? 30000 : 10257;
        const int fstride = isT0 ? 768 : 800;
        const f32x4 zv = {0.f, 0.f, 0.f, 0.f};
        for (int s = isT0 ? fidx : fidx - 768; s < zc; s += fstride) {
            float* base = base0 + (long)zl[s] * LDC;
            for (int j = tid * 4; j + 3 < width; j += 2048)
                __builtin_memcpy(base + j, &zv, 16);
            for (int j = (width & ~3) + tid; j < width; j += 512)
                base[j] = 0.f;
        }
        return;
    }

    const int gid = pid * 3 + (pos == 0 ? 0 : (pos == 3 ? 1 : 2));
    const bool isHead = gid < nblk0;
    const unsigned short* A = isHead ? A0 : A1;
    const unsigned short* B = isHead ? B0 : B1;
    const int nkt   = isHead ? nkt0 : nkt1;
    const int lda   = isHead ? lda0 : lda1;
    const int ldb   = isHead ? ldb0 : ldb1;
    const int width = isHead ? width0 : width1;
    const int NB    = isHead ? NB0 : NB1;
    const int lbid  = isHead ? gid : gid - nblk0;
    const int nwg   = isHead ? nblk0 : 672 - nblk0;

    const int q = nwg >> 3, r = nwg & 7;
    const int xcd = lbid & 7, loc = lbid >> 3;
    const int L = (xcd < r ? xcd * (q + 1) : r * (q + 1) + (xcd - r) * q) + loc;
    const int g = L / (NB * 4);
    const int t = L - g * (NB * 4);
    const long bm = g * 4 + (t & 3);
    const long bn = t >> 2;

    const long bmRow = bm * 256;
    const long bnRow = bn * 256;

    const int scol = (((tid & 7) ^ ((tid >> 3) & 7)) << 3);

    const unsigned lane15 = lane & 15;
    const unsigned rsw   = (lane15 & 7) << 4;
    const unsigned kcol0 = (((lane >> 4) << 4)) ^ rsw;
    const unsigned kcol1 = (64u + ((lane >> 4) << 4)) ^ rsw;
    const unsigned smemBase =
        (unsigned)(size_t)(__attribute__((address_space(3))) char*)smem;
    const unsigned aB0 = smemBase + wr * 16384 + lane15 * 128;
    const unsigned bB0 = smemBase + 32768 + (wc >> 1) * 16384 +
                         ((wc & 1) * 64 + lane15) * 128;

    f32x4 acc[8][4];
#pragma unroll
    for (int m = 0; m < 8; m++)
#pragma unroll
        for (int n = 0; n < 4; n++) acc[m][n] = (f32x4){0.f, 0.f, 0.f, 0.f};

    STAGE2(A, lda, bmRow,       scol, 0);
    STAGE2(A, lda, bmRow + 128, scol, 16384);
    STAGE2(B, ldb, bnRow,       scol, 32768);
    STAGE2(B, ldb, bnRow + 128, scol, 49152);

    short8 afk0[4], afk1[4], bA0[2], bA1[2], bH0[2], bH1[2];

    for (int kt = 0; kt < nkt; ++kt) {
        const int c  = kt & 1;
        const bool pf = (kt + 1) < nkt;
        const int kc = (kt + 1) * 64 + scol;
        const unsigned aBase = aB0 + c * 65536;
        const unsigned bBase = bB0 + c * 65536;
        const unsigned lOff  = (c ^ 1) * 65536;

        // phase 0 : Q0
        if (pf) {
            STAGE2(A, lda, bmRow, kc, lOff);
            asm volatile("s_waitcnt vmcnt(2)" ::: "memory");
        } else {
            asm volatile("s_waitcnt vmcnt(0)" ::: "memory");
        }
        __builtin_amdgcn_s_barrier();
#pragma unroll
        for (int mf = 0; mf < 4; ++mf) {
            afk0[mf] = dsr128(aBase + mf * 2048 + kcol0);
            afk1[mf] = dsr128(aBase + mf * 2048 + kcol1);
        }
#pragma unroll
        for (int nf = 0; nf < 2; ++nf) {
            bA0[nf] = dsr128(bBase + nf * 2048 + kcol0);
            bA1[nf] = dsr128(bBase + nf * 2048 + kcol1);
        }
        asm volatile("s_waitcnt lgkmcnt(0)" ::: "memory");
        __builtin_amdgcn_sched_barrier(0);
        __builtin_amdgcn_s_setprio(1);
#pragma unroll
        for (int mf = 0; mf < 4; ++mf)
#pragma unroll
            for (int nf = 0; nf < 2; ++nf) {
                acc[mf][nf] = mfma16(bA0[nf], afk0[mf], acc[mf][nf]);
                acc[mf][nf] = mfma16(bA1[nf], afk1[mf], acc[mf][nf]);
            }
        __builtin_amdgcn_s_setprio(0);
        __builtin_amdgcn_s_barrier();

        // phase 1 : Q1
#pragma unroll
        for (int nf = 0; nf < 2; ++nf) {
            bH0[nf] = dsr128(bBase + (2 + nf) * 2048 + kcol0);
            bH1[nf] = dsr128(bBase + (2 + nf) * 2048 + kcol1);
        }
        if (pf) STAGE2(A, lda, bmRow + 128, kc, lOff + 16384);
        __builtin_amdgcn_s_barrier();
        asm volatile("s_waitcnt lgkmcnt(0)" ::: "memory");
        __builtin_amdgcn_sched_barrier(0);
        __builtin_amdgcn_s_setprio(1);
#pragma unroll
        for (int mf = 0; mf < 4; ++mf)
#pragma unroll
            for (int nf = 0; nf < 2; ++nf) {
                acc[mf][2 + nf] = mfma16(bH0[nf], afk0[mf], acc[mf][2 + nf]);
                acc[mf][2 + nf] = mfma16(bH1[nf], afk1[mf], acc[mf][2 + nf]);
            }
        __builtin_amdgcn_s_setprio(0);
        __builtin_amdgcn_s_barrier();

        // phase 2 : Q2
#pragma unroll
        for (int mf = 0; mf < 4; ++mf) {
            afk0[mf] = dsr128(aBase + (4 + mf) * 2048 + kcol0);
            afk1[mf] = dsr128(aBase + (4 + mf) * 2048 + kcol1);
        }
        if (pf) STAGE2(B, ldb, bnRow, kc, lOff + 32768);
        __builtin_amdgcn_s_barrier();
        asm volatile("s_waitcnt lgkmcnt(0)" ::: "memory");
        __builtin_amdgcn_sched_barrier(0);
        __builtin_amdgcn_s_setprio(1);
#pragma unroll
        for (int mf = 0; mf < 4; ++mf)
#pragma unroll
            for (int nf = 0; nf < 2; ++nf) {
                acc[4 + mf][2 + nf] = mfma16(bH0[nf], afk0[mf], acc[4 + mf][2 + nf]);
                acc[4 + mf][2 + nf] = mfma16(bH1[nf], afk1[mf], acc[4 + mf][2 + nf]);
            }
        __builtin_amdgcn_s_setprio(0);
        __builtin_amdgcn_s_barrier();

        // phase 3 : Q3
#pragma unroll
        for (int nf = 0; nf < 2; ++nf) {
            bA0[nf] = dsr128(bBase + nf * 2048 + kcol0);
            bA1[nf] = dsr128(bBase + nf * 2048 + kcol1);
        }
        if (pf) STAGE2(B, ldb, bnRow + 128, kc, lOff + 49152);
        __builtin_amdgcn_s_barrier();
        asm volatile("s_waitcnt lgkmcnt(0)" ::: "memory");
        __builtin_amdgcn_sched_barrier(0);
        __builtin_amdgcn_s_setprio(1);
#pragma unroll
        for (int mf = 0; mf < 4; ++mf)
#pragma unroll
            for (int nf = 0; nf < 2; ++nf) {
                acc[4 + mf][nf] = mfma16(bA0[nf], afk0[mf], acc[4 + mf][nf]);
                acc[4 + mf][nf] = mfma16(bA1[nf], afk1[mf], acc[4 + mf][nf]);
            }
        __builtin_amdgcn_s_setprio(0);
        __builtin_amdgcn_s_barrier();
    }

    const int cb4 = (lane >> 4) << 2;
    if (isHead) {
        // transposed coalesced epilogue: LDS [128][256] f32, 2 passes
        for (int h = 0; h < 2; ++h) {
            __syncthreads();
            if (wr == h) {
#pragma unroll
                for (int mf = 0; mf < 8; ++mf) {
                    const int rl = mf * 16 + (int)lane15;
#pragma unroll
                    for (int nf = 0; nf < 4; ++nf) {
                        const int slot = wc * 16 + nf * 4 + (lane >> 4);
                        const int sl = slot ^ (rl & 7);
                        *(f32x4*)(smem + rl * 1024 + sl * 16) = acc[mf][nf];
                    }
                }
            }
            __syncthreads();
            const int colBase = (int)bnRow + lane * 4;
#pragma unroll
            for (int it = 0; it < 16; ++it) {
                const int rl = wave * 16 + it;
                const int sl = lane ^ (rl & 7);
                const f32x4 v = *(const f32x4*)(smem + rl * 1024 + sl * 16);
                float* rp = C0 + (bmRow + h * 128 + rl) * LDC;
                if (colBase + 3 < width) {
                    __builtin_memcpy(rp + colBase, &v, 16);
                } else {
#pragma unroll
                    for (int j = 0; j < 4; ++j)
                        if (colBase + j < width) rp[colBase + j] = v[j];
                }
            }
        }
    } else {
#pragma unroll
        for (int mf = 0; mf < 8; ++mf) {
            const long grow = bmRow + wr * 128 + mf * 16 + lane15;
            unsigned short* rp = C1 + grow * ldc1;
#pragma unroll
            for (int nf = 0; nf < 4; ++nf) {
                const int gcb = (int)bnRow + wc * 64 + nf * 16 + cb4;
                const f32x4 v = acc[mf][nf];
                ushort4 o;
                o.x = f2bf(v[0]); o.y = f2bf(v[1]); o.z = f2bf(v[2]); o.w = f2bf(v[3]);
                if (gcb + 3 < width) {
                    *(ushort4*)(rp + gcb) = o;
                } else {
                    unsigned short tmp[4] = {o.x, o.y, o.z, o.w};
#pragma unroll
                    for (int j = 0; j < 4; ++j)
                        if (gcb + j < width) rp[gcb + j] = tmp[j];
                }
            }
        }
    }
}

// ===========================================================================
// L3: compacted tails, BK=64, rule-21 swizzled staging/reads, transposed
// coalesced epilogue with PLAIN stores (NT reverted).
// ===========================================================================
__global__ __launch_bounds__(256)
void gemm_tails_kernel(const unsigned short* __restrict__ A0,
                       const unsigned short* __restrict__ B0,
                       float* __restrict__ C0,
                       int K0, int lda0, int width0, int NB0, int nblk0,
                       const unsigned short* __restrict__ A1,
                       const unsigned short* __restrict__ B1,
                       float* __restrict__ C1,
                       int K1, int lda1, int width1, int NB1,
                       const int* __restrict__ in0,
                       const int* __restrict__ in1,
                       const int* __restrict__ cnts) {
    __shared__ char tsm[32768];

    const int tid  = threadIdx.x;
    const int lane = tid & 63;
    const int wave = tid >> 6;
    const int wr   = wave >> 1;
    const int wc   = wave & 1;

    const bool is0 = (int)blockIdx.x < nblk0;
    const unsigned short* A = is0 ? A0 : A1;
    const unsigned short* B = is0 ? B0 : B1;
    float* Cf               = is0 ? C0 : C1;
    const int* rowlist      = is0 ? in0 : in1;
    const int cnt           = cnts[is0 ? 0 : 1];
    const int K     = is0 ? K0 : K1;
    const int lda   = is0 ? lda0 : lda1;
    const int width = is0 ? width0 : width1;
    const int NB    = is0 ? NB0 : NB1;
    const int lbid  = is0 ? blockIdx.x : blockIdx.x - nblk0;
    const int nwg   = is0 ? nblk0 : (int)gridDim.x - nblk0;

    const int q = nwg >> 3, r = nwg & 7;
    const int xcd = lbid & 7, loc = lbid >> 3;
    const int L = (xcd < r ? xcd * (q + 1) : r * (q + 1) + (xcd - r) * q) + loc;
    const int g = L / (NB << 3);
    const int t = L - g * (NB << 3);
    const long bm = (g << 3) + (t & 7);
    const long bn = t >> 3;

    if ((int)(bm * 128) >= cnt) return;

    const int cm1 = cnt - 1;
    const int s_row = tid >> 3;                          // 0..31
    const int sc    = (((tid & 7) ^ (s_row & 7)) << 3);  // elem col

    int ar[4];
#pragma unroll
    for (int gg = 0; gg < 4; ++gg) {
        const int gi = (int)(bm * 128) + s_row + 32 * gg;
        ar[gg] = rowlist[gi < cnt ? gi : cm1];
    }
    const unsigned short* pB0 = B + (bn * 128 + s_row) * (long)K + sc;

    f32x4 acc[4][4];
#pragma unroll
    for (int m = 0; m < 4; m++)
#pragma unroll
        for (int n = 0; n < 4; n++) acc[m][n] = (f32x4){0.f, 0.f, 0.f, 0.f};

    const int f_r = lane & 15;
    const int fkb = (lane >> 4) << 4;   // byte offset of k-chunk in half

    for (int k0 = 0; k0 < K; k0 += 64) {
#pragma unroll
        for (int gg = 0; gg < 4; ++gg) {
            gload16(A + (long)ar[gg] * lda + sc + k0,
                    tsm + gg * 4096 + wave * 1024);
            gload16(pB0 + (long)(32 * gg) * K + k0,
                    tsm + 16384 + gg * 4096 + wave * 1024);
        }
        __syncthreads();

#pragma unroll
        for (int h = 0; h < 2; ++h) {
            short8 af[4], bfr[4];
#pragma unroll
            for (int m = 0; m < 4; m++) {
                const int row = wr * 64 + m * 16 + f_r;
                const int cb = (h * 64 + fkb) ^ ((row & 7) << 4);
                af[m] = *(const short8*)(tsm + row * 128 + cb);
            }
#pragma unroll
            for (int n = 0; n < 4; n++) {
                const int row = wc * 64 + n * 16 + f_r;
                const int cb = (h * 64 + fkb) ^ ((row & 7) << 4);
                bfr[n] = *(const short8*)(tsm + 16384 + row * 128 + cb);
            }
#pragma unroll
            for (int m = 0; m < 4; m++)
#pragma unroll
                for (int n = 0; n < 4; n++)
                    acc[m][n] = mfma16(bfr[n], af[m], acc[m][n]);
        }
        __syncthreads();
    }

    // ---- transposed coalesced epilogue: LDS [64][128] f32, 2 passes ----
    const int c_a  = lane & 15;
    const int colL = (lane & 31) * 4;
    for (int h = 0; h < 2; ++h) {
        __syncthreads();
        if (wr == h) {
#pragma unroll
            for (int m = 0; m < 4; ++m) {
                const int rl = m * 16 + c_a;
#pragma unroll
                for (int n = 0; n < 4; ++n) {
                    const int slot = wc * 16 + n * 4 + (lane >> 4);
                    const int sl = slot ^ (rl & 7);
                    *(f32x4*)(tsm + rl * 512 + sl * 16) = acc[m][n];
                }
            }
        }
        __syncthreads();
#pragma unroll
        for (int it = 0; it < 8; ++it) {
            const int rl = wave * 16 + it * 2 + (lane >> 5);
            const int gri = (int)(bm * 128) + h * 64 + rl;
            if (gri < cnt) {
                const int sl = (lane & 31) ^ (rl & 7);
                const f32x4 v = *(const f32x4*)(tsm + rl * 512 + sl * 16);
                const long orow = rowlist[gri];
                float* rp = Cf + orow * LDC;
                const int col = (int)(bn * 128) + colL;
                if (col + 3 < width) {
                    __builtin_memcpy(rp + col, &v, 16);
                } else {
#pragma unroll
                    for (int j = 0; j < 4; ++j)
                        if (col + j < width) rp[col + j] = v[j];
                }
            }
        }
    }
}

extern "C" void kernel_launch(void* const* d_in, const int* in_sizes, int n_in,
                              void* d_out, int out_size, void* d_ws, size_t ws_size,
                              hipStream_t stream) {
    const float* x      = (const float*)d_in[0];   // [4096,1024]
    const int*   target = (const int*)  d_in[1];   // [4096]
    const float* head_w = (const float*)d_in[2];   // [10002,1024]
    const float* t0_w1  = (const float*)d_in[3];   // [256,1024]
    const float* t0_w2  = (const float*)d_in[4];   // [30000,256]
    const float* t1_w1  = (const float*)d_in[5];   // [64,1024]
    const float* t1_w2  = (const float*)d_in[6];   // [10257,64]
    float* out = (float*)d_out;

    // ---- ws layout (bytes) ----
    char* ws = (char*)d_ws;
    unsigned short* xb    = (unsigned short*)(ws + 0);          // 4096x1024
    unsigned short* hwb   = (unsigned short*)(ws + 8388608);    // 10240x1024
    unsigned short* w01b  = (unsigned short*)(ws + 29360128);   // 512x1024 (t0w1|t1w1|0)
    unsigned short* t0w2b = (unsigned short*)(ws + 30408704);   // 30208x256
    unsigned short* t1w2b = (unsigned short*)(ws + 45875200);   // 10496x64
    unsigned short* h01   = (unsigned short*)(ws + 47218688);   // 4096x384 bf16
    int*            in0   = (int*)(ws + 50364416);              // 4096
    int*            z0l   = (int*)(ws + 50380800);              // 4096
    int*            in1   = (int*)(ws + 50397184);              // 4096
    int*            z1l   = (int*)(ws + 50413568);              // 4096
    int*            cnts  = (int*)(ws + 50429952);              // 2

    // ---- L0+L1 merged: scan (block 0) + casts (blocks 1..1536) ----
    CastArgs ca;
    ca.s[0] = {x,      nullptr, xb,    4096,  4096,  524288,  10, 0};
    ca.s[1] = {head_w, nullptr, hwb,   10002, 10002, 1310720, 10, 0};
    ca.s[2] = {t0_w1,  t1_w1,   w01b,  256,   320,   65536,   10, 0};
    ca.s[3] = {t0_w2,  nullptr, t0w2b, 30000, 30000, 966656,  8,  0};
    ca.s[4] = {t1_w2,  nullptr, t1w2b, 10257, 10257, 83968,   6,  0};
    ca.grand8 = 524288 + 1310720 + 65536 + 966656 + 83968;  // 2951168
    scan_cast_kernel<<<dim3(1537), 1024, 0, stream>>>(
        ca, target, out + 4096L * LDC, in0, z0l, in1, z1l, cnts);

    // ---- L2: head (640) + h01 (32) GEMM blocks + 1568 fill blocks ----
    gemm8_dual_kernel<<<dim3(2240), 512, 0, stream>>>(
        xb, hwb, out, 16, 1024, 1024, 10002, 40, 640,
        xb, w01b, h01, 16, 1024, 1024, 384L, 384, 2,
        z0l, z1l, cnts, out);

    // ---- L3: compacted tails only (BK=64) ----
    gemm_tails_kernel<<<dim3(10112), 256, 0, stream>>>(
        h01,       t0w2b, out + 10002, 256, 384, 30000, 235, 7520,
        h01 + 256, t1w2b, out + 40002, 64,  384, 10257, 81,
        in0, in1, cnts);
}